// Round 5
// baseline (228.900 us; speedup 1.0000x reference)
//
#include <hip/hip_runtime.h>

#define BATCH 4
#define LEN   1024
#define KNB   30
#define CH    128
#define EIN   434
#define KP    448      // padded K
#define KST   14       // k-steps of 32
#define ASTR  456      // A row stride in ushorts (228 words = 4 mod 32 banks; mult of 8 for 16B align)
#define CSTR  132      // C row stride in floats

typedef unsigned short ushort_t;
typedef __attribute__((ext_vector_type(8))) short bf16x8;
typedef __attribute__((ext_vector_type(4))) float f32x4;

// PAIRS atom indices: N=0, Ca=1, C=2, O=3, Cb=4
__constant__ int c_pa[24] = {0,2,3,4,1,1,1,1,0,0,0,4,4,3,0,2,3,4,2,3,4,2,3,2};
__constant__ int c_pb[24] = {0,2,3,4,0,2,3,4,2,3,4,2,3,2,1,1,1,1,0,0,0,4,4,3};

struct F3 { float x, y, z; };
__device__ __forceinline__ F3 f3sub(F3 a, F3 b){ return {a.x-b.x, a.y-b.y, a.z-b.z}; }
__device__ __forceinline__ F3 f3cross(F3 a, F3 b){
  return {a.y*b.z - a.z*b.y, a.z*b.x - a.x*b.z, a.x*b.y - a.y*b.x};
}
__device__ __forceinline__ float f3dot(F3 a, F3 b){ return a.x*b.x + a.y*b.y + a.z*b.z; }
__device__ __forceinline__ F3 f3norm(F3 a){
  float n = sqrtf(f3dot(a,a));
  if (n > 0.f) return {a.x/n, a.y/n, a.z/n};
  return {0.f, 0.f, 0.f};
}
__device__ __forceinline__ float fsign(float x){ return (x > 0.f) ? 1.f : ((x < 0.f) ? -1.f : 0.f); }
__device__ __forceinline__ float clip1(float c){ return fminf(fmaxf(c, -1.f + 1e-7f), 1.f - 1e-7f); }
__device__ __forceinline__ float dihedralf(F3 ua, F3 ub, F3 uc){
  F3 n0 = f3norm(f3cross(ua, ub));
  F3 n1 = f3norm(f3cross(ub, uc));
  float cd = clip1(f3dot(n0, n1));
  F3 v = f3norm(f3cross(n0, n1));
  return fsign(-f3dot(v, ub)) * acosf(cd);
}
__device__ __forceinline__ ushort_t f2bf(float f){   // RNE (used once for W pack)
  unsigned u = __float_as_uint(f);
  unsigned r = u + 0x7FFFu + ((u >> 16) & 1u);
  return (ushort_t)(r >> 16);
}
// pack two floats -> two bf16 (round-half-up; 2 VALU ops/value)
__device__ __forceinline__ unsigned pk2(float a, float b){
  unsigned ua = (__float_as_uint(a) + 0x8000u) >> 16;
  unsigned ub = (__float_as_uint(b) + 0x8000u) & 0xFFFF0000u;
  return ua | ub;
}

// Wave-wide u32 min via DPP (VALU pipe). Result uniform.
#define DPP_MIN_STEP(v, ctrl) do{                                            \
    unsigned t_ = (unsigned)__builtin_amdgcn_update_dpp(                     \
        (int)0xFFFFFFFF, (int)(v), (ctrl), 0xF, 0xF, false);                 \
    (v) = t_ < (v) ? t_ : (v);                                               \
  } while(0)
__device__ __forceinline__ unsigned wave_min_u32(unsigned v){
  DPP_MIN_STEP(v, 0x111);   // row_shr:1
  DPP_MIN_STEP(v, 0x112);   // row_shr:2
  DPP_MIN_STEP(v, 0x114);   // row_shr:4
  DPP_MIN_STEP(v, 0x118);   // row_shr:8
  DPP_MIN_STEP(v, 0x142);   // row_bcast:15
  DPP_MIN_STEP(v, 0x143);   // row_bcast:31
  return (unsigned)__builtin_amdgcn_readlane((int)v, 63);
}

// ---------------------------------------------------------------------------
// Blocks 0..1023: wave-per-node top-30 (DPP).  Blocks 1024..1051: W pack.
__global__ __launch_bounds__(256) void topk_kernel(
    const float* __restrict__ X, const float* __restrict__ We,
    float* __restrict__ wDn, int* __restrict__ wIdx, float* __restrict__ outI,
    ushort_t* __restrict__ Wfrag)
{
  if (blockIdx.x >= 1024){
    int f = (blockIdx.x - 1024)*256 + threadIdx.x;
    if (f >= 8*KST*64) return;
    int t = f / (KST*64);
    int s = (f / 64) % KST;
    int l = f & 63;
    int n  = t*16 + (l & 15);
    int k0 = s*32 + (l >> 4)*8;
    ushort_t v[8];
    #pragma unroll
    for (int j = 0; j < 8; ++j){
      int k = k0 + j;
      v[j] = (k < EIN) ? f2bf(We[(size_t)k*CH + n]) : (ushort_t)0;
    }
    ulong2* dst = (ulong2*)(Wfrag + (size_t)f*8);
    *dst = *(ulong2*)v;
    return;
  }

  int wid = threadIdx.x >> 6, l = threadIdx.x & 63;
  int bi = blockIdx.x*4 + wid;
  int b  = bi >> 10;
  const float* pi = X + (size_t)bi*12 + 3;
  float cx = pi[0], cy = pi[1], cz = pi[2];
  const float* Xb = X + (size_t)b*LEN*12;

  unsigned D[16];
  #pragma unroll
  for (int t = 0; t < 16; ++t){
    int j = l + 64*t;
    const float* pj = Xb + (size_t)j*12 + 3;
    float dx = cx - pj[0], dy = cy - pj[1], dz = cz - pj[2];
    D[t] = __float_as_uint(sqrtf(dx*dx + dy*dy + dz*dz + 1e-6f));
  }
  unsigned lmin = D[0]; unsigned jmin = (unsigned)l;
  #pragma unroll
  for (int t = 1; t < 16; ++t)
    if (D[t] < lmin){ lmin = D[t]; jmin = (unsigned)(l + 64*t); }

  for (int k = 0; k < KNB; ++k){
    unsigned dmin = wave_min_u32(lmin);
    unsigned cand = (lmin == dmin) ? jmin : 0xFFFFFFFFu;
    unsigned jwin = wave_min_u32(cand);
    if (cand == jwin){
      wIdx[bi*KNB + k] = (int)jwin;
      wDn[bi*KNB + k]  = __uint_as_float(dmin);
      outI[bi*KNB + k] = (float)jwin;
      int tw = (int)(jwin >> 6);
      #pragma unroll
      for (int t = 0; t < 16; ++t) if (t == tw) D[t] = 0xFFFFFFFFu;
      lmin = D[0]; jmin = (unsigned)l;
      #pragma unroll
      for (int t = 1; t < 16; ++t)
        if (D[t] < lmin){ lmin = D[t]; jmin = (unsigned)(l + 64*t); }
    }
  }
}

// ---------------------------------------------------------------------------
// Fused per-node kernel (256 threads): stage neighbors (recompute Cb/Q from X),
// build 30x434 bf16 features (packed b128 LDS writes), MFMA vs Wfrag, LN
// epilogue for edges; node features + node matmul + node LN fused in.
__global__ __launch_bounds__(256) void fused_kernel(
    const float* __restrict__ X, const float* __restrict__ mask,
    const int* __restrict__ resi, const int* __restrict__ chain,
    const float* __restrict__ Wp, const float* __restrict__ bp,
    const float* __restrict__ ge, const float* __restrict__ be,
    const float* __restrict__ Wn, const float* __restrict__ gn,
    const float* __restrict__ bn,
    const float* __restrict__ wDn, const int* __restrict__ wIdx,
    const ushort_t* __restrict__ Wfrag,
    float* __restrict__ outV, float* __restrict__ outE)
{
  __shared__ __align__(16) ushort_t As[32*ASTR];   // 29184 B; reused as C (f32)
  __shared__ float sAI[15];
  __shared__ float sQi[9];
  __shared__ float sVn[22];
  __shared__ float sAJ[KNB][15];
  __shared__ float sQj[KNB][9];
  __shared__ int   sOffI[KNB];
  __shared__ float sChain[KNB];
  __shared__ float sMaskJ[KNB];
  __shared__ float sDn[KNB];

  int bi  = blockIdx.x;
  int b   = bi >> 10;
  int n   = bi & (LEN - 1);
  int tid = threadIdx.x;

  if (tid < KNB){
    int j  = wIdx[bi*KNB + tid];
    int gj = (b << 10) + j;
    const float4* pj4 = (const float4*)(X + (size_t)gj*12);
    float4 p0 = pj4[0], p1 = pj4[1], p2 = pj4[2];
    F3 Na = {p0.x, p0.y, p0.z};
    F3 Ca = {p0.w, p1.x, p1.y};
    F3 Cc = {p1.z, p1.w, p2.x};
    F3 Oa = {p2.y, p2.z, p2.w};
    sAJ[tid][0]=Na.x; sAJ[tid][1]=Na.y; sAJ[tid][2]=Na.z;
    sAJ[tid][3]=Ca.x; sAJ[tid][4]=Ca.y; sAJ[tid][5]=Ca.z;
    sAJ[tid][6]=Cc.x; sAJ[tid][7]=Cc.y; sAJ[tid][8]=Cc.z;
    sAJ[tid][9]=Oa.x; sAJ[tid][10]=Oa.y; sAJ[tid][11]=Oa.z;
    F3 bv = f3sub(Ca, Na);
    F3 cv = f3sub(Cc, Ca);
    F3 av = f3cross(bv, cv);
    sAJ[tid][12] = -0.58273431f*av.x + 0.56802827f*bv.x - 0.54067466f*cv.x + Ca.x;
    sAJ[tid][13] = -0.58273431f*av.y + 0.56802827f*bv.y - 0.54067466f*cv.y + Ca.y;
    sAJ[tid][14] = -0.58273431f*av.z + 0.56802827f*bv.z - 0.54067466f*cv.z + Ca.z;
    if (j < LEN - 1){
      F3 u0 = f3norm(bv), u1 = f3norm(cv);
      F3 b1 = f3norm(f3sub(u0, u1));
      F3 n0 = f3norm(f3cross(u0, u1));
      F3 r2 = f3cross(b1, n0);
      sQj[tid][0]=b1.x; sQj[tid][1]=b1.y; sQj[tid][2]=b1.z;
      sQj[tid][3]=n0.x; sQj[tid][4]=n0.y; sQj[tid][5]=n0.z;
      sQj[tid][6]=r2.x; sQj[tid][7]=r2.y; sQj[tid][8]=r2.z;
    } else {
      #pragma unroll
      for (int t = 0; t < 9; ++t) sQj[tid][t] = 0.f;
    }
    sOffI[tid]  = resi[bi] - resi[gj];
    sChain[tid] = (chain[bi] == chain[gj]) ? 1.f : 0.f;
    sMaskJ[tid] = mask[gj];
    sDn[tid]    = wDn[bi*KNB + tid];
  } else if (tid == KNB){
    const float4* pi4 = (const float4*)(X + (size_t)bi*12);
    float4 p0 = pi4[0], p1 = pi4[1], p2 = pi4[2];
    F3 Na = {p0.x, p0.y, p0.z};
    F3 Ca = {p0.w, p1.x, p1.y};
    F3 Cc = {p1.z, p1.w, p2.x};
    F3 Oa = {p2.y, p2.z, p2.w};
    sAI[0]=Na.x; sAI[1]=Na.y; sAI[2]=Na.z;
    sAI[3]=Ca.x; sAI[4]=Ca.y; sAI[5]=Ca.z;
    sAI[6]=Cc.x; sAI[7]=Cc.y; sAI[8]=Cc.z;
    sAI[9]=Oa.x; sAI[10]=Oa.y; sAI[11]=Oa.z;
    F3 bv = f3sub(Ca, Na);
    F3 cv = f3sub(Cc, Ca);
    F3 av = f3cross(bv, cv);
    sAI[12] = -0.58273431f*av.x + 0.56802827f*bv.x - 0.54067466f*cv.x + Ca.x;
    sAI[13] = -0.58273431f*av.y + 0.56802827f*bv.y - 0.54067466f*cv.y + Ca.y;
    sAI[14] = -0.58273431f*av.z + 0.56802827f*bv.z - 0.54067466f*cv.z + Ca.z;
    if (n < LEN - 1){
      F3 u0 = f3norm(bv), u1 = f3norm(cv);
      F3 b1 = f3norm(f3sub(u0, u1));
      F3 n0 = f3norm(f3cross(u0, u1));
      F3 r2 = f3cross(b1, n0);
      sQi[0]=b1.x; sQi[1]=b1.y; sQi[2]=b1.z;
      sQi[3]=n0.x; sQi[4]=n0.y; sQi[5]=n0.z;
      sQi[6]=r2.x; sQi[7]=r2.y; sQi[8]=r2.z;
    } else {
      #pragma unroll
      for (int t = 0; t < 9; ++t) sQi[t] = 0.f;
    }
  } else if (tid == KNB + 1){
    // node features vn[22] (dihedrals, angles, V_direct) -> sVn
    const float* p = X + (size_t)bi*12;
    F3 Na = {p[0], p[1], p[2]};
    F3 Ca = {p[3], p[4], p[5]};
    F3 Cc = {p[6], p[7], p[8]};
    F3 Oa = {p[9], p[10], p[11]};
    F3 bv = f3sub(Ca, Na);
    F3 cv = f3sub(Cc, Ca);
    F3 u0 = f3norm(bv), u1 = f3norm(cv);
    float Q[9];
    if (n < LEN - 1){
      F3 b1 = f3norm(f3sub(u0, u1));
      F3 n0 = f3norm(f3cross(u0, u1));
      F3 r2 = f3cross(b1, n0);
      Q[0]=b1.x; Q[1]=b1.y; Q[2]=b1.z;
      Q[3]=n0.x; Q[4]=n0.y; Q[5]=n0.z;
      Q[6]=r2.x; Q[7]=r2.y; Q[8]=r2.z;
    } else {
      #pragma unroll
      for (int t = 0; t < 9; ++t) Q[t] = 0.f;
    }
    float m = mask[bi];
    bool hp = (n > 0), hn = (n < LEN - 1);
    F3 um1 = {0,0,0}, u2 = {0,0,0}, u3 = {0,0,0};
    if (hp){
      const float* pp = p - 12;
      F3 Cp = {pp[6], pp[7], pp[8]};
      um1 = f3norm(f3sub(Na, Cp));
    }
    if (hn){
      const float* pn = p + 12;
      F3 Nn  = {pn[0], pn[1], pn[2]};
      F3 Can = {pn[3], pn[4], pn[5]};
      u2 = f3norm(f3sub(Nn, Cc));
      u3 = f3norm(f3sub(Can, Nn));
    }
    float D0=0.f, D1=0.f, D2=0.f, A0=0.f, A1=0.f, A2=0.f;
    if (hp){ D0 = dihedralf(um1, u0, u1); A0 = acosf(clip1(f3dot(um1, u0))); }
    if (hn){
      D1 = dihedralf(u0, u1, u2); A1 = acosf(clip1(f3dot(u0, u1)));
      D2 = dihedralf(u1, u2, u3); A2 = acosf(clip1(f3dot(u1, u2)));
    }
    sVn[0] = cosf(D0)*m; sVn[1] = cosf(D1)*m; sVn[2]  = cosf(D2)*m;
    sVn[3] = sinf(D0)*m; sVn[4] = sinf(D1)*m; sVn[5]  = sinf(D2)*m;
    sVn[6] = cosf(A0)*m; sVn[7] = cosf(A1)*m; sVn[8]  = cosf(A2)*m;
    sVn[9] = sinf(A0)*m; sVn[10]= sinf(A1)*m; sVn[11] = sinf(A2)*m;
    F3 dxs[3];
    dxs[0] = {0.f, 0.f, 0.f};
    dxs[1] = f3sub(Cc, Na);
    dxs[2] = f3sub(Oa, Na);
    #pragma unroll
    for (int a = 0; a < 3; ++a){
      F3 dv = dxs[a];
      F3 du = { Q[0]*dv.x + Q[1]*dv.y + Q[2]*dv.z,
                Q[3]*dv.x + Q[4]*dv.y + Q[5]*dv.z,
                Q[6]*dv.x + Q[7]*dv.y + Q[8]*dv.z };
      F3 dn = f3norm(du);
      sVn[12 + a*3 + 0] = dn.x * m;
      sVn[12 + a*3 + 1] = dn.y * m;
      sVn[12 + a*3 + 2] = dn.z * m;
    }
    sVn[21] = m;
  } else if (tid >= 32 && tid < 144){
    // zero rows 30,31 (cols 0..447): 112 x 16B chunks
    int idx = tid - 32;
    int r = 30 + (idx / 56), ch = idx % 56;
    *(uint4*)&As[r*ASTR + ch*8] = make_uint4(0,0,0,0);
  } else if (tid >= 144 && tid < 144 + KNB){
    // zero pad cols 434..447 of row r
    int r = tid - 144;
    ushort_t* row = &As[r*ASTR];
    *(unsigned*)&row[434] = 0u;
    *(uint2*)&row[436] = make_uint2(0,0);
    *(uint4*)&row[440] = make_uint4(0,0,0,0);
  }
  __syncthreads();

  // ---- Phase A: 30 edges x 8 subtasks, packed bf16 writes ----
  if (tid < KNB*8){
    int k = tid >> 3, s = tid & 7;
    ushort_t* row = &As[k*ASTR];
    if (s == 0){
      int off = sOffI[k];
      float ch = sChain[k];
      int d = off + 32;
      d = d < 0 ? 0 : (d > 64 ? 64 : d);
      if (!(ch > 0.5f)) d = 65;
      const float4* wp4 = (const float4*)(Wp + d*16);
      const float4* bp4 = (const float4*)bp;
      float e[16];
      #pragma unroll
      for (int q = 0; q < 4; ++q){
        float4 wv = wp4[q], bv = bp4[q];
        e[q*4+0] = wv.x + bv.x; e[q*4+1] = wv.y + bv.y;
        e[q*4+2] = wv.z + bv.z; e[q*4+3] = wv.w + bv.w;
      }
      *(uint4*)&row[0] = make_uint4(pk2(e[0],e[1]), pk2(e[2],e[3]), pk2(e[4],e[5]), pk2(e[6],e[7]));
      *(uint4*)&row[8] = make_uint4(pk2(e[8],e[9]), pk2(e[10],e[11]), pk2(e[12],e[13]), pk2(e[14],e[15]));
      *(unsigned*)&row[432] = pk2(ch, sMaskJ[k]);
    } else if (s == 1){
      float nx = sAI[0], ny = sAI[1], nz = sAI[2];
      const int amap[4] = {3, 0, 6, 9};
      float e[12];
      #pragma unroll
      for (int a = 0; a < 4; ++a){
        float dx = sAJ[k][amap[a]+0] - nx;
        float dy = sAJ[k][amap[a]+1] - ny;
        float dz = sAJ[k][amap[a]+2] - nz;
        float e0 = sQi[0]*dx + sQi[1]*dy + sQi[2]*dz;
        float e1 = sQi[3]*dx + sQi[4]*dy + sQi[5]*dz;
        float e2 = sQi[6]*dx + sQi[7]*dy + sQi[8]*dz;
        float nn = sqrtf(e0*e0 + e1*e1 + e2*e2);
        float inv = nn > 0.f ? 1.f/nn : 0.f;
        e[a*3+0] = e0*inv; e[a*3+1] = e1*inv; e[a*3+2] = e2*inv;
      }
      *(uint4*)&row[416] = make_uint4(pk2(e[0],e[1]), pk2(e[2],e[3]), pk2(e[4],e[5]), pk2(e[6],e[7]));
      *(uint2*)&row[424] = make_uint2(pk2(e[8],e[9]), pk2(e[10],e[11]));
    } else if (s == 2){
      float R[3][3];
      #pragma unroll
      for (int i2 = 0; i2 < 3; ++i2)
        #pragma unroll
        for (int l2 = 0; l2 < 3; ++l2)
          R[i2][l2] = sQi[0*3+i2]*sQj[k][0*3+l2]
                    + sQi[1*3+i2]*sQj[k][1*3+l2]
                    + sQi[2*3+i2]*sQj[k][2*3+l2];
      float Rxx = R[0][0], Ryy = R[1][1], Rzz = R[2][2];
      float mx = 0.5f*sqrtf(fabsf(1.f + Rxx - Ryy - Rzz));
      float my = 0.5f*sqrtf(fabsf(1.f - Rxx + Ryy - Rzz));
      float mz = 0.5f*sqrtf(fabsf(1.f - Rxx - Ryy + Rzz));
      float qx = fsign(R[2][1] - R[1][2]) * mx;
      float qy = fsign(R[0][2] - R[2][0]) * my;
      float qz = fsign(R[1][0] - R[0][1]) * mz;
      float qw = sqrtf(fmaxf(1.f + Rxx + Ryy + Rzz, 0.f)) * 0.5f;
      float qn = sqrtf(qx*qx + qy*qy + qz*qz + qw*qw);
      float inv = qn > 0.f ? 1.f/qn : 0.f;
      *(uint2*)&row[428] = make_uint2(pk2(qx*inv, qy*inv), pk2(qz*inv, qw*inv));
    }
    for (int p = s; p < 25; p += 8){
      float d;
      if (p == 0) d = sDn[k];
      else {
        int ai = c_pa[p-1]*3, bj = c_pb[p-1]*3;
        float dx = sAI[ai+0] - sAJ[k][bj+0];
        float dy = sAI[ai+1] - sAJ[k][bj+1];
        float dz = sAI[ai+2] - sAJ[k][bj+2];
        d = sqrtf(dx*dx + dy*dy + dz*dz + 1e-6f);
      }
      float e[16];
      #pragma unroll
      for (int m2 = 0; m2 < 16; ++m2){
        float mu = (float)(2.0 + m2 * (20.0/15.0));
        float tt = (d - mu) * 0.8f;
        e[m2] = __expf(-tt*tt);
      }
      *(uint4*)&row[16 + p*16]     = make_uint4(pk2(e[0],e[1]), pk2(e[2],e[3]), pk2(e[4],e[5]), pk2(e[6],e[7]));
      *(uint4*)&row[16 + p*16 + 8] = make_uint4(pk2(e[8],e[9]), pk2(e[10],e[11]), pk2(e[12],e[13]), pk2(e[14],e[15]));
    }
  }
  __syncthreads();

  // ---- Phase B: MFMA. wave w owns ntiles {2w,2w+1} x mtiles {0,1} ----
  int w = tid >> 6, l = tid & 63;
  int n0 = w*2;
  int aOff0 = (l & 15)*ASTR + (l >> 4)*8;
  int aOff1 = aOff0 + 16*ASTR;
  const ushort_t* bp0 = Wfrag + ((size_t)(n0    *KST)*64 + l)*8;
  const ushort_t* bp1 = Wfrag + ((size_t)((n0+1)*KST)*64 + l)*8;

  f32x4 acc00 = {0.f,0.f,0.f,0.f}, acc01 = acc00, acc10 = acc00, acc11 = acc00;

  bf16x8 a0 = *(const bf16x8*)&As[aOff0];
  bf16x8 a1 = *(const bf16x8*)&As[aOff1];
  bf16x8 b0 = *(const bf16x8*)bp0;
  bf16x8 b1 = *(const bf16x8*)bp1;
  #pragma unroll
  for (int s = 0; s < KST; ++s){
    bf16x8 a0n, a1n, b0n, b1n;
    if (s < KST-1){
      int ka = (s+1)*32;
      a0n = *(const bf16x8*)&As[aOff0 + ka];
      a1n = *(const bf16x8*)&As[aOff1 + ka];
      b0n = *(const bf16x8*)(bp0 + (size_t)(s+1)*64*8);
      b1n = *(const bf16x8*)(bp1 + (size_t)(s+1)*64*8);
    }
    acc00 = __builtin_amdgcn_mfma_f32_16x16x32_bf16(a0, b0, acc00, 0, 0, 0);
    acc01 = __builtin_amdgcn_mfma_f32_16x16x32_bf16(a0, b1, acc01, 0, 0, 0);
    acc10 = __builtin_amdgcn_mfma_f32_16x16x32_bf16(a1, b0, acc10, 0, 0, 0);
    acc11 = __builtin_amdgcn_mfma_f32_16x16x32_bf16(a1, b1, acc11, 0, 0, 0);
    if (s < KST-1){ a0 = a0n; a1 = a1n; b0 = b0n; b1 = b1n; }
  }
  __syncthreads();   // all As reads done; reuse as C tile

  float* Cs = (float*)As;       // [32][CSTR]
  int ccol = l & 15, crow = (l >> 4)*4;
  #pragma unroll
  for (int r = 0; r < 4; ++r){
    Cs[(crow + r)*CSTR      + n0*16 + ccol]      = acc00[r];
    Cs[(crow + r)*CSTR      + (n0+1)*16 + ccol]  = acc01[r];
    Cs[(16 + crow + r)*CSTR + n0*16 + ccol]      = acc10[r];
    Cs[(16 + crow + r)*CSTR + (n0+1)*16 + ccol]  = acc11[r];
  }
  __syncthreads();

  // ---- Epilogues: edge LN (tid<240) + node matmul/LN (tid 240..255) ----
  if (tid < KNB*8){
    int row = tid >> 3, g = tid & 7;
    const float4* src = (const float4*)&Cs[row*CSTR + g*16];
    float4 v0 = src[0], v1 = src[1], v2 = src[2], v3 = src[3];
    float v[16] = {v0.x,v0.y,v0.z,v0.w, v1.x,v1.y,v1.z,v1.w,
                   v2.x,v2.y,v2.z,v2.w, v3.x,v3.y,v3.z,v3.w};
    float s = 0.f;
    #pragma unroll
    for (int c = 0; c < 16; ++c) s += v[c];
    #pragma unroll
    for (int off = 1; off < 8; off <<= 1) s += __shfl_xor(s, off, 8);
    float mu = s * (1.f/128.f);
    float vs = 0.f;
    #pragma unroll
    for (int c = 0; c < 16; ++c){ float dd = v[c] - mu; vs += dd*dd; }
    #pragma unroll
    for (int off = 1; off < 8; off <<= 1) vs += __shfl_xor(vs, off, 8);
    float inv = 1.f / sqrtf(vs * (1.f/128.f) + 1e-5f);
    float o[16];
    #pragma unroll
    for (int c = 0; c < 16; ++c)
      o[c] = (v[c] - mu)*inv*ge[g*16 + c] + be[g*16 + c];
    float4* dst = (float4*)&outE[((size_t)bi*KNB + row)*CH + g*16];
    dst[0] = make_float4(o[0], o[1], o[2], o[3]);
    dst[1] = make_float4(o[4], o[5], o[6], o[7]);
    dst[2] = make_float4(o[8], o[9], o[10], o[11]);
    dst[3] = make_float4(o[12], o[13], o[14], o[15]);
  } else if (tid >= 240){
    int c0 = (tid - 240)*8;
    float x[8] = {0,0,0,0,0,0,0,0};
    #pragma unroll
    for (int r = 0; r < 22; ++r){
      float vr = sVn[r];
      float4 w0 = *(const float4*)&Wn[r*CH + c0];
      float4 w1 = *(const float4*)&Wn[r*CH + c0 + 4];
      x[0] = fmaf(vr, w0.x, x[0]); x[1] = fmaf(vr, w0.y, x[1]);
      x[2] = fmaf(vr, w0.z, x[2]); x[3] = fmaf(vr, w0.w, x[3]);
      x[4] = fmaf(vr, w1.x, x[4]); x[5] = fmaf(vr, w1.y, x[5]);
      x[6] = fmaf(vr, w1.z, x[6]); x[7] = fmaf(vr, w1.w, x[7]);
    }
    float s = 0.f;
    #pragma unroll
    for (int c = 0; c < 8; ++c) s += x[c];
    #pragma unroll
    for (int off = 1; off < 16; off <<= 1) s += __shfl_xor(s, off, 16);
    float mu = s * (1.f/128.f);
    float vs = 0.f;
    #pragma unroll
    for (int c = 0; c < 8; ++c){ float dd = x[c] - mu; vs += dd*dd; }
    #pragma unroll
    for (int off = 1; off < 16; off <<= 1) vs += __shfl_xor(vs, off, 16);
    float inv = 1.f / sqrtf(vs * (1.f/128.f) + 1e-5f);
    float o[8];
    #pragma unroll
    for (int c = 0; c < 8; ++c)
      o[c] = (x[c] - mu)*inv*gn[c0 + c] + bn[c0 + c];
    float4* dst = (float4*)&outV[(size_t)bi*CH + c0];
    dst[0] = make_float4(o[0], o[1], o[2], o[3]);
    dst[1] = make_float4(o[4], o[5], o[6], o[7]);
  }
}

extern "C" void kernel_launch(void* const* d_in, const int* in_sizes, int n_in,
                              void* d_out, int out_size, void* d_ws, size_t ws_size,
                              hipStream_t stream)
{
  const float* X    = (const float*)d_in[0];
  const float* mask = (const float*)d_in[1];
  const int*   resi = (const int*)  d_in[2];
  const int*   chn  = (const int*)  d_in[3];
  const float* Wp   = (const float*)d_in[4];
  const float* bp   = (const float*)d_in[5];
  const float* We   = (const float*)d_in[6];
  const float* Wn   = (const float*)d_in[7];
  const float* ge   = (const float*)d_in[8];
  const float* be   = (const float*)d_in[9];
  const float* gn   = (const float*)d_in[10];
  const float* bn   = (const float*)d_in[11];

  float* outV = (float*)d_out;                          // (4,1024,128)
  float* outE = outV + (size_t)BATCH*LEN*CH;            // (4,1024,30,128)
  float* outI = outE + (size_t)BATCH*LEN*KNB*CH;        // (4,1024,30) as float

  float* ws   = (float*)d_ws;
  float* wDn  = ws;                                     // 4096*30
  int*   wIdx = (int*)(wDn + (size_t)BATCH*LEN*KNB);    // 4096*30
  ushort_t* Wfrag = (ushort_t*)(wIdx + (size_t)BATCH*LEN*KNB);  // 8*14*64*8 bf16

  topk_kernel<<<1024 + 28, 256, 0, stream>>>(X, We, wDn, wIdx, outI, Wfrag);
  fused_kernel<<<BATCH*LEN, 256, 0, stream>>>(X, mask, resi, chn, Wp, bp, ge, be,
                                              Wn, gn, bn, wDn, wIdx, Wfrag,
                                              outV, outE);
}

// Round 6
// 193.918 us; speedup vs baseline: 1.1804x; 1.1804x over previous
//
#include <hip/hip_runtime.h>

#define BATCH 4
#define LEN   1024
#define KNB   30
#define CH    128
#define EIN   434
#define KP    448      // padded K
#define KST   14       // k-steps of 32
#define ASTR  456      // A row stride in ushorts (228 words = 4 mod 32 banks; mult of 8 for 16B align)
#define CSTR  132      // C row stride in floats

typedef unsigned short ushort_t;
typedef __attribute__((ext_vector_type(8))) short bf16x8;
typedef __attribute__((ext_vector_type(4))) float f32x4;

// PAIRS atom indices: N=0, Ca=1, C=2, O=3, Cb=4
__constant__ int c_pa[24] = {0,2,3,4,1,1,1,1,0,0,0,4,4,3,0,2,3,4,2,3,4,2,3,2};
__constant__ int c_pb[24] = {0,2,3,4,0,2,3,4,2,3,4,2,3,2,1,1,1,1,0,0,0,4,4,3};

struct F3 { float x, y, z; };
__device__ __forceinline__ F3 f3sub(F3 a, F3 b){ return {a.x-b.x, a.y-b.y, a.z-b.z}; }
__device__ __forceinline__ F3 f3cross(F3 a, F3 b){
  return {a.y*b.z - a.z*b.y, a.z*b.x - a.x*b.z, a.x*b.y - a.y*b.x};
}
__device__ __forceinline__ float f3dot(F3 a, F3 b){ return a.x*b.x + a.y*b.y + a.z*b.z; }
__device__ __forceinline__ F3 f3norm(F3 a){
  float n = sqrtf(f3dot(a,a));
  if (n > 0.f) return {a.x/n, a.y/n, a.z/n};
  return {0.f, 0.f, 0.f};
}
__device__ __forceinline__ float fsign(float x){ return (x > 0.f) ? 1.f : ((x < 0.f) ? -1.f : 0.f); }
__device__ __forceinline__ float clip1(float c){ return fminf(fmaxf(c, -1.f + 1e-7f), 1.f - 1e-7f); }
__device__ __forceinline__ float dihedralf(F3 ua, F3 ub, F3 uc){
  F3 n0 = f3norm(f3cross(ua, ub));
  F3 n1 = f3norm(f3cross(ub, uc));
  float cd = clip1(f3dot(n0, n1));
  F3 v = f3norm(f3cross(n0, n1));
  return fsign(-f3dot(v, ub)) * acosf(cd);
}
__device__ __forceinline__ ushort_t f2bf(float f){   // RNE (W pack)
  unsigned u = __float_as_uint(f);
  unsigned r = u + 0x7FFFu + ((u >> 16) & 1u);
  return (ushort_t)(r >> 16);
}
// pack two floats -> two bf16 (round-half-up; 2 VALU ops/value)
__device__ __forceinline__ unsigned pk2(float a, float b){
  unsigned ua = (__float_as_uint(a) + 0x8000u) >> 16;
  unsigned ub = (__float_as_uint(b) + 0x8000u) & 0xFFFF0000u;
  return ua | ub;
}

// Wave-wide u32 min via DPP (VALU pipe). Result uniform.
#define DPP_MIN_STEP(v, ctrl) do{                                            \
    unsigned t_ = (unsigned)__builtin_amdgcn_update_dpp(                     \
        (int)0xFFFFFFFF, (int)(v), (ctrl), 0xF, 0xF, false);                 \
    (v) = t_ < (v) ? t_ : (v);                                               \
  } while(0)
__device__ __forceinline__ unsigned wave_min_u32(unsigned v){
  DPP_MIN_STEP(v, 0x111);   // row_shr:1
  DPP_MIN_STEP(v, 0x112);   // row_shr:2
  DPP_MIN_STEP(v, 0x114);   // row_shr:4
  DPP_MIN_STEP(v, 0x118);   // row_shr:8
  DPP_MIN_STEP(v, 0x142);   // row_bcast:15
  DPP_MIN_STEP(v, 0x143);   // row_bcast:31
  return (unsigned)__builtin_amdgcn_readlane((int)v, 63);
}

// ---------------------------------------------------------------------------
// Blocks 0..15: per-node prep (Cb, frame Q, node feats, packed Ca).
// Blocks 16..43: pack W_edge into bf16 B-fragment order.
__global__ __launch_bounds__(256) void prep_kernel(
    const float* __restrict__ X, const float* __restrict__ mask,
    const float* __restrict__ We,
    float* __restrict__ wCb, float* __restrict__ wQ, float* __restrict__ wVn,
    float* __restrict__ wCa, ushort_t* __restrict__ Wfrag)
{
  if (blockIdx.x >= 16){
    int f = (blockIdx.x - 16)*256 + threadIdx.x;
    if (f >= 8*KST*64) return;
    int t = f / (KST*64);
    int s = (f / 64) % KST;
    int l = f & 63;
    int n  = t*16 + (l & 15);
    int k0 = s*32 + (l >> 4)*8;
    ushort_t v[8];
    #pragma unroll
    for (int j = 0; j < 8; ++j){
      int k = k0 + j;
      v[j] = (k < EIN) ? f2bf(We[(size_t)k*CH + n]) : (ushort_t)0;
    }
    ulong2* dst = (ulong2*)(Wfrag + (size_t)f*8);
    *dst = *(ulong2*)v;
    return;
  }

  int idx = blockIdx.x * 256 + threadIdx.x;
  int n = idx & (LEN - 1);
  const float* p = X + (size_t)idx * 12;
  F3 Na = {p[0], p[1], p[2]};
  F3 Ca = {p[3], p[4], p[5]};
  F3 Cc = {p[6], p[7], p[8]};
  F3 Oa = {p[9], p[10], p[11]};
  wCa[idx*4+0] = Ca.x; wCa[idx*4+1] = Ca.y; wCa[idx*4+2] = Ca.z; wCa[idx*4+3] = 0.f;
  F3 bv = f3sub(Ca, Na);
  F3 cv = f3sub(Cc, Ca);
  F3 av = f3cross(bv, cv);
  wCb[idx*3+0] = -0.58273431f*av.x + 0.56802827f*bv.x - 0.54067466f*cv.x + Ca.x;
  wCb[idx*3+1] = -0.58273431f*av.y + 0.56802827f*bv.y - 0.54067466f*cv.y + Ca.y;
  wCb[idx*3+2] = -0.58273431f*av.z + 0.56802827f*bv.z - 0.54067466f*cv.z + Ca.z;

  F3 u0 = f3norm(bv);
  F3 u1 = f3norm(cv);

  float Q[9];
  if (n < LEN - 1){
    F3 b1 = f3norm(f3sub(u0, u1));
    F3 n0 = f3norm(f3cross(u0, u1));
    F3 r2 = f3cross(b1, n0);
    Q[0]=b1.x; Q[1]=b1.y; Q[2]=b1.z;
    Q[3]=n0.x; Q[4]=n0.y; Q[5]=n0.z;
    Q[6]=r2.x; Q[7]=r2.y; Q[8]=r2.z;
  } else {
    #pragma unroll
    for (int t = 0; t < 9; ++t) Q[t] = 0.f;
  }
  #pragma unroll
  for (int t = 0; t < 9; ++t) wQ[(size_t)idx*9 + t] = Q[t];

  float m = mask[idx];
  bool hp = (n > 0), hn = (n < LEN - 1);
  F3 um1 = {0,0,0}, u2 = {0,0,0}, u3 = {0,0,0};
  if (hp){
    const float* pp = p - 12;
    F3 Cp = {pp[6], pp[7], pp[8]};
    um1 = f3norm(f3sub(Na, Cp));
  }
  if (hn){
    const float* pn = p + 12;
    F3 Nn  = {pn[0], pn[1], pn[2]};
    F3 Can = {pn[3], pn[4], pn[5]};
    u2 = f3norm(f3sub(Nn, Cc));
    u3 = f3norm(f3sub(Can, Nn));
  }
  float D0=0.f, D1=0.f, D2=0.f, A0=0.f, A1=0.f, A2=0.f;
  if (hp){ D0 = dihedralf(um1, u0, u1); A0 = acosf(clip1(f3dot(um1, u0))); }
  if (hn){
    D1 = dihedralf(u0, u1, u2); A1 = acosf(clip1(f3dot(u0, u1)));
    D2 = dihedralf(u1, u2, u3); A2 = acosf(clip1(f3dot(u1, u2)));
  }
  float vn[22];
  vn[0] = cosf(D0)*m; vn[1] = cosf(D1)*m; vn[2]  = cosf(D2)*m;
  vn[3] = sinf(D0)*m; vn[4] = sinf(D1)*m; vn[5]  = sinf(D2)*m;
  vn[6] = cosf(A0)*m; vn[7] = cosf(A1)*m; vn[8]  = cosf(A2)*m;
  vn[9] = sinf(A0)*m; vn[10]= sinf(A1)*m; vn[11] = sinf(A2)*m;
  F3 dxs[3];
  dxs[0] = {0.f, 0.f, 0.f};
  dxs[1] = f3sub(Cc, Na);
  dxs[2] = f3sub(Oa, Na);
  #pragma unroll
  for (int a = 0; a < 3; ++a){
    F3 dv = dxs[a];
    F3 du = { Q[0]*dv.x + Q[1]*dv.y + Q[2]*dv.z,
              Q[3]*dv.x + Q[4]*dv.y + Q[5]*dv.z,
              Q[6]*dv.x + Q[7]*dv.y + Q[8]*dv.z };
    F3 dn = f3norm(du);
    vn[12 + a*3 + 0] = dn.x * m;
    vn[12 + a*3 + 1] = dn.y * m;
    vn[12 + a*3 + 2] = dn.z * m;
  }
  vn[21] = m;
  #pragma unroll
  for (int t = 0; t < 22; ++t) wVn[(size_t)idx*22 + t] = vn[t];
}

// ---------------------------------------------------------------------------
// Wave-per-node top-30, DPP. Per lane: 16 u32 distance keys; two-phase 32-bit
// wave-min (dist, then index among min-holders) = exact lax.top_k order.
__global__ __launch_bounds__(256) void topk_kernel(
    const float* __restrict__ wCa, float* __restrict__ wDn,
    int* __restrict__ wIdx, float* __restrict__ outI)
{
  int wid = threadIdx.x >> 6, l = threadIdx.x & 63;
  int bi = blockIdx.x*4 + wid;
  int b  = bi >> 10;
  const float4* Ca = (const float4*)wCa;
  float4 ci = Ca[bi];
  const float4* Cb = Ca + (size_t)b * LEN;

  unsigned D[16];
  #pragma unroll
  for (int t = 0; t < 16; ++t){
    int j = l + 64*t;
    float4 cj = Cb[j];
    float dx = ci.x - cj.x, dy = ci.y - cj.y, dz = ci.z - cj.z;
    D[t] = __float_as_uint(sqrtf(dx*dx + dy*dy + dz*dz + 1e-6f));
  }
  unsigned lmin = D[0]; unsigned jmin = (unsigned)l;
  #pragma unroll
  for (int t = 1; t < 16; ++t)
    if (D[t] < lmin){ lmin = D[t]; jmin = (unsigned)(l + 64*t); }

  for (int k = 0; k < KNB; ++k){
    unsigned dmin = wave_min_u32(lmin);
    unsigned cand = (lmin == dmin) ? jmin : 0xFFFFFFFFu;
    unsigned jwin = wave_min_u32(cand);
    if (cand == jwin){
      wIdx[bi*KNB + k] = (int)jwin;
      wDn[bi*KNB + k]  = __uint_as_float(dmin);
      outI[bi*KNB + k] = (float)jwin;
      int tw = (int)(jwin >> 6);
      #pragma unroll
      for (int t = 0; t < 16; ++t) if (t == tw) D[t] = 0xFFFFFFFFu;
      lmin = D[0]; jmin = (unsigned)l;
      #pragma unroll
      for (int t = 1; t < 16; ++t)
        if (D[t] < lmin){ lmin = D[t]; jmin = (unsigned)(l + 64*t); }
    }
  }
}

// ---------------------------------------------------------------------------
// Block per node, 256 threads: stage precomputed per-node data, build 30x434
// bf16 features (packed uint4 LDS writes), MFMA vs Wfrag, LN epilogues for
// edges (240 thr) and node (16 thr).
__global__ __launch_bounds__(256) void edge_kernel(
    const float* __restrict__ X, const float* __restrict__ mask,
    const int* __restrict__ resi, const int* __restrict__ chain,
    const float* __restrict__ Wp, const float* __restrict__ bp,
    const float* __restrict__ ge, const float* __restrict__ be,
    const float* __restrict__ Wn, const float* __restrict__ gn,
    const float* __restrict__ bn,
    const float* __restrict__ wCb, const float* __restrict__ wQ,
    const float* __restrict__ wVn,
    const float* __restrict__ wDn, const int* __restrict__ wIdx,
    const ushort_t* __restrict__ Wfrag,
    float* __restrict__ outV, float* __restrict__ outE)
{
  __shared__ __align__(16) ushort_t As[32*ASTR];   // 29184 B; reused as C (f32)
  __shared__ float sAI[15];
  __shared__ float sQi[9];
  __shared__ float sVn[22];
  __shared__ float sAJ[KNB][15];
  __shared__ float sQj[KNB][9];
  __shared__ int   sOffI[KNB];
  __shared__ float sChain[KNB];
  __shared__ float sMaskJ[KNB];
  __shared__ float sDn[KNB];

  int bi  = blockIdx.x;
  int b   = bi >> 10;
  int tid = threadIdx.x;

  if (tid < KNB){
    int j  = wIdx[bi*KNB + tid];
    int gj = (b << 10) + j;
    const float* pj = X + (size_t)gj * 12;
    #pragma unroll
    for (int t = 0; t < 12; ++t) sAJ[tid][t] = pj[t];
    sAJ[tid][12] = wCb[(size_t)gj*3 + 0];
    sAJ[tid][13] = wCb[(size_t)gj*3 + 1];
    sAJ[tid][14] = wCb[(size_t)gj*3 + 2];
    #pragma unroll
    for (int t = 0; t < 9; ++t) sQj[tid][t] = wQ[(size_t)gj*9 + t];
    sOffI[tid]  = resi[bi] - resi[gj];
    sChain[tid] = (chain[bi] == chain[gj]) ? 1.f : 0.f;
    sMaskJ[tid] = mask[gj];
    sDn[tid]    = wDn[bi*KNB + tid];
  } else if (tid == KNB){
    const float* pi = X + (size_t)bi * 12;
    #pragma unroll
    for (int t = 0; t < 12; ++t) sAI[t] = pi[t];
    sAI[12] = wCb[(size_t)bi*3 + 0];
    sAI[13] = wCb[(size_t)bi*3 + 1];
    sAI[14] = wCb[(size_t)bi*3 + 2];
  } else if (tid == KNB + 1){
    #pragma unroll
    for (int t = 0; t < 9; ++t) sQi[t] = wQ[(size_t)bi*9 + t];
  } else if (tid >= 32 && tid < 54){
    sVn[tid - 32] = wVn[(size_t)bi*22 + (tid - 32)];
  } else if (tid >= 64 && tid < 176){
    // zero rows 30,31 (cols 0..447): 112 x 16B chunks
    int idx = tid - 64;
    int r = 30 + (idx / 56), c8 = idx % 56;
    *(uint4*)&As[r*ASTR + c8*8] = make_uint4(0,0,0,0);
  } else if (tid >= 176 && tid < 176 + KNB){
    // zero pad cols 434..447 of row r
    int r = tid - 176;
    ushort_t* row = &As[r*ASTR];
    *(unsigned*)&row[434] = 0u;
    *(uint2*)&row[436] = make_uint2(0,0);
    *(uint4*)&row[440] = make_uint4(0,0,0,0);
  }
  __syncthreads();

  // ---- Phase A: 30 edges x 8 subtasks, packed bf16 writes ----
  if (tid < KNB*8){
    int k = tid >> 3, s = tid & 7;
    ushort_t* row = &As[k*ASTR];
    if (s == 0){
      int off = sOffI[k];
      float ch = sChain[k];
      int d = off + 32;
      d = d < 0 ? 0 : (d > 64 ? 64 : d);
      if (!(ch > 0.5f)) d = 65;
      const float4* wp4 = (const float4*)(Wp + d*16);
      const float4* bp4 = (const float4*)bp;
      float e[16];
      #pragma unroll
      for (int q = 0; q < 4; ++q){
        float4 wv = wp4[q], bv = bp4[q];
        e[q*4+0] = wv.x + bv.x; e[q*4+1] = wv.y + bv.y;
        e[q*4+2] = wv.z + bv.z; e[q*4+3] = wv.w + bv.w;
      }
      *(uint4*)&row[0] = make_uint4(pk2(e[0],e[1]), pk2(e[2],e[3]), pk2(e[4],e[5]), pk2(e[6],e[7]));
      *(uint4*)&row[8] = make_uint4(pk2(e[8],e[9]), pk2(e[10],e[11]), pk2(e[12],e[13]), pk2(e[14],e[15]));
      *(unsigned*)&row[432] = pk2(ch, sMaskJ[k]);
    } else if (s == 1){
      float nx = sAI[0], ny = sAI[1], nz = sAI[2];
      const int amap[4] = {3, 0, 6, 9};
      float e[12];
      #pragma unroll
      for (int a = 0; a < 4; ++a){
        float dx = sAJ[k][amap[a]+0] - nx;
        float dy = sAJ[k][amap[a]+1] - ny;
        float dz = sAJ[k][amap[a]+2] - nz;
        float e0 = sQi[0]*dx + sQi[1]*dy + sQi[2]*dz;
        float e1 = sQi[3]*dx + sQi[4]*dy + sQi[5]*dz;
        float e2 = sQi[6]*dx + sQi[7]*dy + sQi[8]*dz;
        float nn = sqrtf(e0*e0 + e1*e1 + e2*e2);
        float inv = nn > 0.f ? 1.f/nn : 0.f;
        e[a*3+0] = e0*inv; e[a*3+1] = e1*inv; e[a*3+2] = e2*inv;
      }
      *(uint4*)&row[416] = make_uint4(pk2(e[0],e[1]), pk2(e[2],e[3]), pk2(e[4],e[5]), pk2(e[6],e[7]));
      *(uint2*)&row[424] = make_uint2(pk2(e[8],e[9]), pk2(e[10],e[11]));
    } else if (s == 2){
      float R[3][3];
      #pragma unroll
      for (int i2 = 0; i2 < 3; ++i2)
        #pragma unroll
        for (int l2 = 0; l2 < 3; ++l2)
          R[i2][l2] = sQi[0*3+i2]*sQj[k][0*3+l2]
                    + sQi[1*3+i2]*sQj[k][1*3+l2]
                    + sQi[2*3+i2]*sQj[k][2*3+l2];
      float Rxx = R[0][0], Ryy = R[1][1], Rzz = R[2][2];
      float mx = 0.5f*sqrtf(fabsf(1.f + Rxx - Ryy - Rzz));
      float my = 0.5f*sqrtf(fabsf(1.f - Rxx + Ryy - Rzz));
      float mz = 0.5f*sqrtf(fabsf(1.f - Rxx - Ryy + Rzz));
      float qx = fsign(R[2][1] - R[1][2]) * mx;
      float qy = fsign(R[0][2] - R[2][0]) * my;
      float qz = fsign(R[1][0] - R[0][1]) * mz;
      float qw = sqrtf(fmaxf(1.f + Rxx + Ryy + Rzz, 0.f)) * 0.5f;
      float qn = sqrtf(qx*qx + qy*qy + qz*qz + qw*qw);
      float inv = qn > 0.f ? 1.f/qn : 0.f;
      *(uint2*)&row[428] = make_uint2(pk2(qx*inv, qy*inv), pk2(qz*inv, qw*inv));
    }
    for (int p = s; p < 25; p += 8){
      float d;
      if (p == 0) d = sDn[k];
      else {
        int ai = c_pa[p-1]*3, bj = c_pb[p-1]*3;
        float dx = sAI[ai+0] - sAJ[k][bj+0];
        float dy = sAI[ai+1] - sAJ[k][bj+1];
        float dz = sAI[ai+2] - sAJ[k][bj+2];
        d = sqrtf(dx*dx + dy*dy + dz*dz + 1e-6f);
      }
      float e[16];
      #pragma unroll
      for (int m2 = 0; m2 < 16; ++m2){
        float mu = (float)(2.0 + m2 * (20.0/15.0));
        float tt = (d - mu) * 0.8f;
        e[m2] = __expf(-tt*tt);
      }
      *(uint4*)&row[16 + p*16]     = make_uint4(pk2(e[0],e[1]), pk2(e[2],e[3]), pk2(e[4],e[5]), pk2(e[6],e[7]));
      *(uint4*)&row[16 + p*16 + 8] = make_uint4(pk2(e[8],e[9]), pk2(e[10],e[11]), pk2(e[12],e[13]), pk2(e[14],e[15]));
    }
  }
  __syncthreads();

  // ---- Phase B: MFMA. wave w owns ntiles {2w,2w+1} x mtiles {0,1} ----
  int w = tid >> 6, l = tid & 63;
  int n0 = w*2;
  int aOff0 = (l & 15)*ASTR + (l >> 4)*8;
  int aOff1 = aOff0 + 16*ASTR;
  const ushort_t* bp0 = Wfrag + ((size_t)(n0    *KST)*64 + l)*8;
  const ushort_t* bp1 = Wfrag + ((size_t)((n0+1)*KST)*64 + l)*8;

  f32x4 acc00 = {0.f,0.f,0.f,0.f}, acc01 = acc00, acc10 = acc00, acc11 = acc00;

  bf16x8 a0 = *(const bf16x8*)&As[aOff0];
  bf16x8 a1 = *(const bf16x8*)&As[aOff1];
  bf16x8 b0 = *(const bf16x8*)bp0;
  bf16x8 b1 = *(const bf16x8*)bp1;
  #pragma unroll
  for (int s = 0; s < KST; ++s){
    bf16x8 a0n, a1n, b0n, b1n;
    if (s < KST-1){
      int ka = (s+1)*32;
      a0n = *(const bf16x8*)&As[aOff0 + ka];
      a1n = *(const bf16x8*)&As[aOff1 + ka];
      b0n = *(const bf16x8*)(bp0 + (size_t)(s+1)*64*8);
      b1n = *(const bf16x8*)(bp1 + (size_t)(s+1)*64*8);
    }
    acc00 = __builtin_amdgcn_mfma_f32_16x16x32_bf16(a0, b0, acc00, 0, 0, 0);
    acc01 = __builtin_amdgcn_mfma_f32_16x16x32_bf16(a0, b1, acc01, 0, 0, 0);
    acc10 = __builtin_amdgcn_mfma_f32_16x16x32_bf16(a1, b0, acc10, 0, 0, 0);
    acc11 = __builtin_amdgcn_mfma_f32_16x16x32_bf16(a1, b1, acc11, 0, 0, 0);
    if (s < KST-1){ a0 = a0n; a1 = a1n; b0 = b0n; b1 = b1n; }
  }
  __syncthreads();   // all As reads done; reuse as C tile

  float* Cs = (float*)As;       // [32][CSTR]
  int ccol = l & 15, crow = (l >> 4)*4;
  #pragma unroll
  for (int r = 0; r < 4; ++r){
    Cs[(crow + r)*CSTR      + n0*16 + ccol]      = acc00[r];
    Cs[(crow + r)*CSTR      + (n0+1)*16 + ccol]  = acc01[r];
    Cs[(16 + crow + r)*CSTR + n0*16 + ccol]      = acc10[r];
    Cs[(16 + crow + r)*CSTR + (n0+1)*16 + ccol]  = acc11[r];
  }
  __syncthreads();

  // ---- Epilogues: edge LN (tid<240) + node matmul/LN (tid 240..255) ----
  if (tid < KNB*8){
    int row = tid >> 3, g = tid & 7;
    const float4* src = (const float4*)&Cs[row*CSTR + g*16];
    float4 v0 = src[0], v1 = src[1], v2 = src[2], v3 = src[3];
    float v[16] = {v0.x,v0.y,v0.z,v0.w, v1.x,v1.y,v1.z,v1.w,
                   v2.x,v2.y,v2.z,v2.w, v3.x,v3.y,v3.z,v3.w};
    float s = 0.f;
    #pragma unroll
    for (int c = 0; c < 16; ++c) s += v[c];
    #pragma unroll
    for (int off = 1; off < 8; off <<= 1) s += __shfl_xor(s, off, 8);
    float mu = s * (1.f/128.f);
    float vs = 0.f;
    #pragma unroll
    for (int c = 0; c < 16; ++c){ float dd = v[c] - mu; vs += dd*dd; }
    #pragma unroll
    for (int off = 1; off < 8; off <<= 1) vs += __shfl_xor(vs, off, 8);
    float inv = 1.f / sqrtf(vs * (1.f/128.f) + 1e-5f);
    float o[16];
    #pragma unroll
    for (int c = 0; c < 16; ++c)
      o[c] = (v[c] - mu)*inv*ge[g*16 + c] + be[g*16 + c];
    float4* dst = (float4*)&outE[((size_t)bi*KNB + row)*CH + g*16];
    dst[0] = make_float4(o[0], o[1], o[2], o[3]);
    dst[1] = make_float4(o[4], o[5], o[6], o[7]);
    dst[2] = make_float4(o[8], o[9], o[10], o[11]);
    dst[3] = make_float4(o[12], o[13], o[14], o[15]);
  } else if (tid >= 240){
    int c0 = (tid - 240)*8;
    float x[8] = {0,0,0,0,0,0,0,0};
    #pragma unroll
    for (int r = 0; r < 22; ++r){
      float vr = sVn[r];
      float4 w0 = *(const float4*)&Wn[r*CH + c0];
      float4 w1 = *(const float4*)&Wn[r*CH + c0 + 4];
      x[0] = fmaf(vr, w0.x, x[0]); x[1] = fmaf(vr, w0.y, x[1]);
      x[2] = fmaf(vr, w0.z, x[2]); x[3] = fmaf(vr, w0.w, x[3]);
      x[4] = fmaf(vr, w1.x, x[4]); x[5] = fmaf(vr, w1.y, x[5]);
      x[6] = fmaf(vr, w1.z, x[6]); x[7] = fmaf(vr, w1.w, x[7]);
    }
    float s = 0.f;
    #pragma unroll
    for (int c = 0; c < 8; ++c) s += x[c];
    #pragma unroll
    for (int off = 1; off < 16; off <<= 1) s += __shfl_xor(s, off, 16);
    float mu = s * (1.f/128.f);
    float vs = 0.f;
    #pragma unroll
    for (int c = 0; c < 8; ++c){ float dd = x[c] - mu; vs += dd*dd; }
    #pragma unroll
    for (int off = 1; off < 16; off <<= 1) vs += __shfl_xor(vs, off, 16);
    float inv = 1.f / sqrtf(vs * (1.f/128.f) + 1e-5f);
    float o[8];
    #pragma unroll
    for (int c = 0; c < 8; ++c)
      o[c] = (x[c] - mu)*inv*gn[c0 + c] + bn[c0 + c];
    float4* dst = (float4*)&outV[(size_t)bi*CH + c0];
    dst[0] = make_float4(o[0], o[1], o[2], o[3]);
    dst[1] = make_float4(o[4], o[5], o[6], o[7]);
  }
}

extern "C" void kernel_launch(void* const* d_in, const int* in_sizes, int n_in,
                              void* d_out, int out_size, void* d_ws, size_t ws_size,
                              hipStream_t stream)
{
  const float* X    = (const float*)d_in[0];
  const float* mask = (const float*)d_in[1];
  const int*   resi = (const int*)  d_in[2];
  const int*   chn  = (const int*)  d_in[3];
  const float* Wp   = (const float*)d_in[4];
  const float* bp   = (const float*)d_in[5];
  const float* We   = (const float*)d_in[6];
  const float* Wn   = (const float*)d_in[7];
  const float* ge   = (const float*)d_in[8];
  const float* be   = (const float*)d_in[9];
  const float* gn   = (const float*)d_in[10];
  const float* bn   = (const float*)d_in[11];

  float* outV = (float*)d_out;                          // (4,1024,128)
  float* outE = outV + (size_t)BATCH*LEN*CH;            // (4,1024,30,128)
  float* outI = outE + (size_t)BATCH*LEN*KNB*CH;        // (4,1024,30) as float

  float* ws   = (float*)d_ws;
  float* wCb  = ws;                                     // 4096*3
  float* wQ   = wCb + (size_t)BATCH*LEN*3;              // 4096*9
  float* wVn  = wQ  + (size_t)BATCH*LEN*9;              // 4096*22
  float* wDn  = wVn + (size_t)BATCH*LEN*22;             // 4096*30
  int*   wIdx = (int*)(wDn + (size_t)BATCH*LEN*KNB);    // 4096*30
  float* wCa  = (float*)(wIdx + (size_t)BATCH*LEN*KNB); // 4096*4
  ushort_t* Wfrag = (ushort_t*)(wCa + (size_t)BATCH*LEN*4);  // 8*14*64*8 bf16

  prep_kernel<<<16 + 28, 256, 0, stream>>>(X, mask, We, wCb, wQ, wVn, wCa, Wfrag);
  topk_kernel<<<BATCH*LEN/4, 256, 0, stream>>>(wCa, wDn, wIdx, outI);
  edge_kernel<<<BATCH*LEN, 256, 0, stream>>>(X, mask, resi, chn, Wp, bp, ge, be,
                                             Wn, gn, bn, wCb, wQ, wVn,
                                             wDn, wIdx, Wfrag, outV, outE);
}